// Round 5
// baseline (256.140 us; speedup 1.0000x reference)
//
#include <hip/hip_runtime.h>

#define NWG     32
#define NTHR    256
#define HIDDEN  256
#define HPW     8      // h indices per WG
#define ENC_T   16
#define NTOK    28
#define DECLEN  25

typedef unsigned long long u64;

__device__ __forceinline__ float sigf(float x){ return 1.0f/(1.0f + expf(-x)); }
__device__ __forceinline__ float4 ld4(const float* p){ return *(const float4*)p; }

__device__ __forceinline__ void astore(u64* p, u64 v){
  __hip_atomic_store(p, v, __ATOMIC_RELAXED, __HIP_MEMORY_SCOPE_AGENT);
}
__device__ __forceinline__ u64 aload(const u64* p){
  return __hip_atomic_load(p, __ATOMIC_RELAXED, __HIP_MEMORY_SCOPE_AGENT);
}

__global__ __launch_bounds__(NTHR, 1) void vae_lstm_kernel(
    const int* __restrict__ data, const int* __restrict__ data_c, const int* __restrict__ target_c,
    const float* __restrict__ cond_emb, const float* __restrict__ enc_emb,
    const float* __restrict__ eWih, const float* __restrict__ eWhh,
    const float* __restrict__ ebih, const float* __restrict__ ebhh,
    const float* __restrict__ hmuW, const float* __restrict__ hmub,
    const float* __restrict__ cmuW, const float* __restrict__ cmub,
    const float* __restrict__ fc1W, const float* __restrict__ fc1b,
    const float* __restrict__ fc2W, const float* __restrict__ fc2b,
    const float* __restrict__ dec_emb, const float* __restrict__ dWih,
    const float* __restrict__ dWhh, const float* __restrict__ dbih, const float* __restrict__ dbhh,
    const float* __restrict__ outW, const float* __restrict__ outb,
    float* __restrict__ out, u64* __restrict__ hb, u64* __restrict__ cb)
{
  __shared__ __align__(16) float h_sh[HIDDEN];
  __shared__ __align__(16) float c2_sh[HIDDEN];
  __shared__ float pxe_sh[ENC_T][32];
  __shared__ float pxd_sh[NTOK][32];
  __shared__ float mu_sh[64];
  __shared__ float l_sh[NTOK];
  __shared__ float tc_sh[8];
  __shared__ float outb_sh[NTOK];

  const int w   = blockIdx.x;
  const int tid = threadIdx.x;
  // ---- prologue/logits mapping (R1/R4-identical) ----
  const int r   = tid >> 3;        // 0..31
  const int p   = tid & 7;         // 32-col chunk
  const int gate_o = r >> 3;
  const int j_o    = r & 7;
  const int grow_o = gate_o*HIDDEN + w*HPW + j_o;
  // ---- main-loop mapping: all 4 gates of an h-index in one wave ----
  const int W    = tid >> 6;       // wave 0..3
  const int L    = tid & 63;       // lane
  const int g    = L >> 4;         // gate 0..3 (i,f,g,o)
  const int jj   = (L >> 3) & 1;   // 2 h per wave
  const int j_in = W*2 + jj;       // 0..7
  const int j_gl = w*HPW + j_in;   // global h index
  const int growm = g*HIDDEN + j_gl;
  const int b16  = L & 15;

  // ---------------- prologue ----------------
  float4 wenc[8], wdec[8], wout[8];
  #pragma unroll
  for (int k=0;k<8;++k){
    const int c = (p*8+k)*4;
    wenc[k] = ld4(eWhh + (size_t)growm*HIDDEN + c);
    wdec[k] = ld4(dWhh + (size_t)growm*HIDDEN + c);
  }
  if (r < NTOK){
    #pragma unroll
    for (int k=0;k<8;++k) wout[k] = ld4(outW + (size_t)r*HIDDEN + (p*8+k)*4);
  } else {
    #pragma unroll
    for (int k=0;k<8;++k) wout[k] = make_float4(0.f,0.f,0.f,0.f);
  }

  // px encoder (R4-identical serial order, thread (r,p) mapping)
  {
    const float bsum = ebih[grow_o] + ebhh[grow_o];
    for (int ss = p; ss < ENC_T; ss += 8){
      const float* x  = enc_emb + (size_t)data[ss]*HIDDEN;
      const float* Wr = eWih + (size_t)grow_o*HIDDEN;
      float a = bsum;
      for (int c4=0;c4<64;++c4){
        float4 wv = ld4(Wr + c4*4); float4 xv = ld4(x + c4*4);
        a = fmaf(wv.x,xv.x, fmaf(wv.y,xv.y, fmaf(wv.z,xv.z, fmaf(wv.w,xv.w, a))));
      }
      pxe_sh[ss][r] = a;
    }
  }
  // px decoder, all 28 tokens (R4-identical)
  {
    const float bsum = dbih[grow_o] + dbhh[grow_o];
    for (int tk = p; tk < NTOK; tk += 8){
      const float* x  = dec_emb + (size_t)tk*HIDDEN;
      const float* Wr = dWih + (size_t)grow_o*HIDDEN;
      float a = bsum;
      for (int c4=0;c4<64;++c4){
        float4 wv = ld4(Wr + c4*4); float4 xv = ld4(x + c4*4);
        a = fmaf(wv.x,fmaxf(xv.x,0.f), fmaf(wv.y,fmaxf(xv.y,0.f),
            fmaf(wv.z,fmaxf(xv.z,0.f), fmaf(wv.w,fmaxf(xv.w,0.f), a))));
      }
      pxd_sh[tk][r] = a;
    }
  }

  const int dcnd = data_c[0];
  if (tid < 8)    tc_sh[tid]   = cond_emb[target_c[0]*8 + tid];
  if (tid < NTOK) outb_sh[tid] = outb[tid];
  h_sh[tid] = (tid >= HIDDEN-8) ? cond_emb[dcnd*8 + (tid-(HIDDEN-8))] : 0.f;
  float c = (j_gl >= HIDDEN-8) ? cond_emb[dcnd*8 + (j_gl-(HIDDEN-8))] : 0.f;
  __syncthreads();

  int step = 1;
  // ---------------- encoder: 16 steps, 2 barriers each ----------------
  for (int es=0; es<ENC_T; ++es, ++step){
    const float4* h4 = (const float4*)h_sh;
    float a = 0.f;
    #pragma unroll
    for (int k=0;k<8;++k){
      float4 hv = h4[p*8+k]; float4 wv = wenc[k];
      a = fmaf(wv.x,hv.x, fmaf(wv.y,hv.y, fmaf(wv.z,hv.z, fmaf(wv.w,hv.w, a))));
    }
    a += __shfl_xor(a,1); a += __shfl_xor(a,2); a += __shfl_xor(a,4);
    a += pxe_sh[es][(g<<3)|j_in];
    float gi = __shfl(a, b16);
    float gf = __shfl(a, 16|b16);
    float gg = __shfl(a, 32|b16);
    float go = __shfl(a, 48|b16);
    float cc = sigf(gf)*c + sigf(gi)*tanhf(gg);
    float hh = sigf(go)*tanhf(cc);
    c = cc;
    if (g==0 && p==0){
      astore(&hb[(step&1)*HIDDEN + j_gl], ((u64)step<<32) | (u64)__float_as_uint(hh));
      if (es==ENC_T-1)
        astore(&cb[j_gl], ((u64)step<<32) | (u64)__float_as_uint(cc));
    }
    __syncthreads();                       // all h_sh reads done
    if (W==0){                             // single-wave poller
      u64* base = hb + (step&1)*HIDDEN;
      u64 v0,v1,v2,v3; bool done=false;
      do{
        if(!done){
          v0=aload(base+2*L); v1=aload(base+2*L+1);
          v2=aload(base+128+2*L); v3=aload(base+128+2*L+1);
          done = ((unsigned)(v0>>32)==(unsigned)step)&&((unsigned)(v1>>32)==(unsigned)step)
              && ((unsigned)(v2>>32)==(unsigned)step)&&((unsigned)(v3>>32)==(unsigned)step);
        }
      } while(!__all(done));
      h_sh[2*L]     = __uint_as_float((unsigned)v0);
      h_sh[2*L+1]   = __uint_as_float((unsigned)v1);
      h_sh[128+2*L]   = __uint_as_float((unsigned)v2);
      h_sh[128+2*L+1] = __uint_as_float((unsigned)v3);
    }
    __syncthreads();                       // h_sh ready
  }

  // ---------------- mid (redundant per WG; R4-identical arithmetic) ----------------
  {
    u64 v;
    do { v = aload(&cb[tid]); } while ((unsigned)(v>>32) != (unsigned)ENC_T);
    c2_sh[tid] = __uint_as_float((unsigned)v);
  }
  __syncthreads();
  {
    int row = tid>>2, q = tid&3;
    const float* Wr = (row<32) ? (hmuW + (size_t)row*HIDDEN) : (cmuW + (size_t)(row-32)*HIDDEN);
    const float* v  = (row<32) ? h_sh : c2_sh;
    float a=0.f;
    for (int c4=q*16; c4<q*16+16; ++c4){
      float4 wv = ld4(Wr + c4*4);
      float4 vv = *(const float4*)(v + c4*4);
      a = fmaf(wv.x,vv.x, fmaf(wv.y,vv.y, fmaf(wv.z,vv.z, fmaf(wv.w,vv.w, a))));
    }
    a += __shfl_xor(a,1); a += __shfl_xor(a,2);
    if (q==0) mu_sh[row] = a + ((row<32)? hmub[row] : cmub[row-32]);
  }
  __syncthreads();
  {
    float a = fc1b[tid];
    const float* Wr = fc1W + (size_t)tid*40;
    #pragma unroll
    for (int k=0;k<32;++k) a = fmaf(Wr[k], mu_sh[k], a);
    #pragma unroll
    for (int k=0;k<8;++k)  a = fmaf(Wr[32+k], tc_sh[k], a);
    // fc2 row for THIS lane's h-index (R4-identical scalar order, redundant x8 lanes)
    float a2 = fc2b[j_gl];
    const float* W2 = fc2W + (size_t)j_gl*40;
    #pragma unroll
    for (int k=0;k<32;++k) a2 = fmaf(W2[k], mu_sh[32+k], a2);
    #pragma unroll
    for (int k=0;k<8;++k)  a2 = fmaf(W2[32+k], tc_sh[k], a2);
    __syncthreads();
    h_sh[tid] = a;                 // decoder h0
    c = a2;                        // decoder c0 (register, per-lane row)
    __syncthreads();
  }

  // decoder pre-dot (h-part of step 0, overlapping nothing yet)
  float a_pend;
  {
    const float4* h4 = (const float4*)h_sh;
    float t = 0.f;
    #pragma unroll
    for (int k=0;k<8;++k){
      float4 hv = h4[p*8+k]; float4 wv = wdec[k];
      t = fmaf(wv.x,hv.x, fmaf(wv.y,hv.y, fmaf(wv.z,hv.z, fmaf(wv.w,hv.w, t))));
    }
    t += __shfl_xor(t,1); t += __shfl_xor(t,2); t += __shfl_xor(t,4);
    a_pend = t;
  }
  __syncthreads();                 // h_sh reads done before first poll-write

  // ---------------- decoder: 25 steps, 2 barriers each ----------------
  int tok = 0; // SOS
  for (int dt=0; dt<DECLEN; ++dt, ++step){
    float a = a_pend + pxd_sh[tok][(g<<3)|j_in];
    float gi = __shfl(a, b16);
    float gf = __shfl(a, 16|b16);
    float gg = __shfl(a, 32|b16);
    float go = __shfl(a, 48|b16);
    float cc = sigf(gf)*c + sigf(gi)*tanhf(gg);
    float hh = sigf(go)*tanhf(cc);
    c = cc;
    if (g==0 && p==0)
      astore(&hb[(step&1)*HIDDEN + j_gl], ((u64)step<<32) | (u64)__float_as_uint(hh));
    if (W==0){
      u64* base = hb + (step&1)*HIDDEN;
      u64 v0,v1,v2,v3; bool done=false;
      do{
        if(!done){
          v0=aload(base+2*L); v1=aload(base+2*L+1);
          v2=aload(base+128+2*L); v3=aload(base+128+2*L+1);
          done = ((unsigned)(v0>>32)==(unsigned)step)&&((unsigned)(v1>>32)==(unsigned)step)
              && ((unsigned)(v2>>32)==(unsigned)step)&&((unsigned)(v3>>32)==(unsigned)step);
        }
      } while(!__all(done));
      h_sh[2*L]     = __uint_as_float((unsigned)v0);
      h_sh[2*L+1]   = __uint_as_float((unsigned)v1);
      h_sh[128+2*L]   = __uint_as_float((unsigned)v2);
      h_sh[128+2*L+1] = __uint_as_float((unsigned)v3);
    }
    __syncthreads();               // h_t ready in h_sh
    // overlapped: next gate-dot (wdec) + logits-dot (wout), shared h reads
    {
      const float4* h4 = (const float4*)h_sh;
      float t = 0.f, la = 0.f;
      #pragma unroll
      for (int k=0;k<8;++k){
        float4 hv = h4[p*8+k];
        float4 wv = wdec[k];
        t  = fmaf(wv.x,hv.x, fmaf(wv.y,hv.y, fmaf(wv.z,hv.z, fmaf(wv.w,hv.w, t))));
        float4 ov = wout[k];
        la = fmaf(ov.x,hv.x, fmaf(ov.y,hv.y, fmaf(ov.z,hv.z, fmaf(ov.w,hv.w, la))));
      }
      t += __shfl_xor(t,1); t += __shfl_xor(t,2); t += __shfl_xor(t,4);
      a_pend = t;
      la += __shfl_xor(la,1); la += __shfl_xor(la,2); la += __shfl_xor(la,4);
      if (p==0 && r < NTOK) l_sh[r] = la + outb_sh[r];
    }
    __syncthreads();               // l_sh ready; h_sh reads done
    // argmax redundantly on every thread (R4-identical compare semantics)
    {
      float best = l_sh[0]; int bi = 0;
      #pragma unroll
      for (int i=1;i<NTOK;++i){ if (l_sh[i] > best){ best = l_sh[i]; bi = i; } }
      tok = bi;
    }
    if (w==0){
      if (tid < NTOK) out[dt*NTOK + tid] = l_sh[tid];
      if (tid==0)     out[DECLEN*NTOK + dt] = (float)tok;
    }
  }
}

extern "C" void kernel_launch(void* const* d_in, const int* in_sizes, int n_in,
                              void* d_out, int out_size, void* d_ws, size_t ws_size,
                              hipStream_t stream)
{
  u64* hb = (u64*)d_ws;                        // double-buffered tagged h: 2*256 u64 (4 KB)
  u64* cb = (u64*)((char*)d_ws + 4096);        // tagged cT: 256 u64 (2 KB)
  hipMemsetAsync(d_ws, 0, 6144, stream);       // clear tags every launch

  vae_lstm_kernel<<<NWG, NTHR, 0, stream>>>(
    (const int*)d_in[0], (const int*)d_in[1], (const int*)d_in[2],
    (const float*)d_in[3], (const float*)d_in[4],
    (const float*)d_in[5], (const float*)d_in[6], (const float*)d_in[7], (const float*)d_in[8],
    (const float*)d_in[9], (const float*)d_in[10], (const float*)d_in[11], (const float*)d_in[12],
    (const float*)d_in[13], (const float*)d_in[14], (const float*)d_in[15], (const float*)d_in[16],
    (const float*)d_in[17], (const float*)d_in[18], (const float*)d_in[19], (const float*)d_in[20],
    (const float*)d_in[21], (const float*)d_in[22], (const float*)d_in[23],
    (float*)d_out, hb, cb);
}